// Round 3
// baseline (46619.431 us; speedup 1.0000x reference)
//
#include <hip/hip_runtime.h>
#include <hip/hip_bf16.h>
#include <math.h>

// GRU_74758200754229: 2-layer GRU (B=128, T=1024, F=256, H=512) + final linear.
// v4: per-step launches; each WG owns j-pair (j0,j0+1) for BOTH layers;
// lane = 2 batches (full 128-b per wave); h/x staged to LDS in 32-k
// double-buffered chunks (issue-early / write-late); weights in LDS read as
// wave-uniform b128 broadcasts; 4-way k-split per layer + LDS reduction.

#define T_LEN 1024
#define B_SZ  128
#define F_IN  256
#define H_SZ  512

#define NCH   16      // chunks per step
#define CHK   32      // h-k per chunk
#define XCH   16      // x-k per chunk

// LDS float offsets
#define WL0_OFF 0                 // [6 rows][768]  (Whh0 | Wih0)
#define WL1_OFF 4608              // [6 rows][1024] (Whh1 | Wih1)
#define BUF0    10752             // buf: h0[32][128] h1[32][128] x[16][128] = 10240 floats
#define BUF1    20992
#define RB_OFF  31232             // [6 slots][16][64] = 6144 floats
#define LDS_FLOATS 37376
#define LDS_BYTES  (LDS_FLOATS * 4)   // 149504 B <= 160 KiB -> 1 WG/CU

#define HBUF (H_SZ * B_SZ)        // one h buffer: [512 j][128 b] floats

__device__ __forceinline__ float sigm(float v) { return 1.f / (1.f + __expf(-v)); }

struct StageRegs { float4 h0a, h0b, h1a, h1b, xv; };

// Issue global loads for chunk c (held in registers across the compute phase).
__device__ __forceinline__ void stage_issue(StageRegs& st,
    const float* __restrict__ h0p, const float* __restrict__ h1p,
    const float* __restrict__ x, int c, int sx, int tid)
{
  const float* p0 = h0p + c * (CHK * B_SZ);
  const float* p1 = h1p + c * (CHK * B_SZ);
  st.h0a = *(const float4*)(p0 + (tid << 2));
  st.h0b = *(const float4*)(p0 + 2048 + (tid << 2));
  st.h1a = *(const float4*)(p1 + (tid << 2));
  st.h1b = *(const float4*)(p1 + 2048 + (tid << 2));
  const int b  = tid >> 2;
  const int ks = (tid & 3) << 2;
  st.xv = *(const float4*)(x + ((long)b * T_LEN + sx) * F_IN + c * XCH + ks);
}

// Write staged registers into LDS buffer (write-late, just before barrier).
__device__ __forceinline__ void stage_commit(const StageRegs& st,
                                             float* __restrict__ buf, int tid)
{
  *(float4*)(buf + (tid << 2))        = st.h0a;
  *(float4*)(buf + 2048 + (tid << 2)) = st.h0b;
  *(float4*)(buf + 4096 + (tid << 2)) = st.h1a;
  *(float4*)(buf + 6144 + (tid << 2)) = st.h1b;
  const int b  = tid >> 2;
  const int ks = (tid & 3) << 2;
  float* xb = buf + 8192;               // transposed [16 k][128 b]
  xb[(ks + 0) * B_SZ + b] = st.xv.x;    // 4-way bank conflict, 4 instrs - cheap
  xb[(ks + 1) * B_SZ + b] = st.xv.y;
  xb[(ks + 2) * B_SZ + b] = st.xv.z;
  xb[(ks + 3) * B_SZ + b] = st.xv.w;
}

// 6 weight rows (3 gates x 2 j) x NK k-steps x 2 batches per lane.
// acc[16]: idx = ((g4*2+jj)*2+bb), g4: 0=r, 1=z, 2=n(h-part), 3=n(x-part).
template<int NK, int ROWLEN>
__device__ __forceinline__ void dot6(float (&acc)[16],
    const float* __restrict__ hc, int kloc0,
    const float* __restrict__ wl, int col0, int lane2, bool nx)
{
  float4 wA[6], wB[6];
  #pragma unroll
  for (int r = 0; r < 6; ++r) {
    wA[r] = *(const float4*)(wl + r * ROWLEN + col0);          // uniform b128
    if (NK == 8) wB[r] = *(const float4*)(wl + r * ROWLEN + col0 + 4);
  }
  #pragma unroll
  for (int k = 0; k < NK; ++k) {
    const float2 hv = *(const float2*)(hc + (kloc0 + k) * B_SZ + lane2);
    #pragma unroll
    for (int r = 0; r < 6; ++r) {
      const int g  = r >> 1, jj = r & 1;
      const int g4 = (g == 2 && nx) ? 3 : g;
      const float w = (k < 4) ? ((const float*)&wA[r])[k]
                              : ((const float*)&wB[r])[k - 4];
      acc[((g4 * 2 + jj) << 1) + 0] = fmaf(w, hv.x, acc[((g4 * 2 + jj) << 1) + 0]);
      acc[((g4 * 2 + jj) << 1) + 1] = fmaf(w, hv.y, acc[((g4 * 2 + jj) << 1) + 1]);
    }
  }
}

// Block 512 = 8 waves: L = wave>>2 (0: layer0@t=s, 1: layer1@t=s-1),
// kq = wave&3 (k-quarter). Grid 256 = j-pairs.
__global__ void __launch_bounds__(512, 2)
gru_step(int s,
         const float* __restrict__ x,
         const float* __restrict__ Wih0, const float* __restrict__ Whh0,
         const float* __restrict__ bih0, const float* __restrict__ bhh0,
         const float* __restrict__ Wih1, const float* __restrict__ Whh1,
         const float* __restrict__ bih1, const float* __restrict__ bhh1,
         const float* __restrict__ h0p, float* __restrict__ h0w,
         const float* __restrict__ h1p, float* __restrict__ h1w)
{
  extern __shared__ float lds[];
  const int tid   = threadIdx.x;
  const int wave  = tid >> 6;
  const int lane  = tid & 63;
  const int lane2 = lane << 1;
  const int L     = wave >> 2;
  const int kq    = wave & 3;
  const int j0    = blockIdx.x << 1;

  const bool l0_act  = (s < T_LEN);
  const bool l0h_act = (s >= 1) && l0_act;
  const bool l1_act  = (s >= 1);
  const bool l1h_act = (s >= 2);
  const int  sx      = (s < T_LEN) ? s : (T_LEN - 1);

  // ---- prologue: weights -> LDS (once per step) --------------------------
  for (int sl = tid; sl < 1152; sl += 512) {        // L0: 6 x 768
    const int row  = sl / 192;
    const int col  = (sl % 192) << 2;
    const int grow = (row >> 1) * H_SZ + j0 + (row & 1);
    float4 v;
    if (col < 512) v = *(const float4*)(Whh0 + (long)grow * H_SZ + col);
    else           v = *(const float4*)(Wih0 + (long)grow * F_IN + (col - 512));
    *(float4*)(lds + WL0_OFF + row * 768 + col) = v;
  }
  for (int sl = tid; sl < 1536; sl += 512) {        // L1: 6 x 1024
    const int row  = sl >> 8;
    const int col  = (sl & 255) << 2;
    const int grow = (row >> 1) * H_SZ + j0 + (row & 1);
    float4 v;
    if (col < 512) v = *(const float4*)(Whh1 + (long)grow * H_SZ + col);
    else           v = *(const float4*)(Whh1 != Wih1 ? Wih1 + (long)grow * H_SZ + (col - 512)
                                                     : Wih1);
    *(float4*)(lds + WL1_OFF + row * 1024 + col) = v;
  }

  // ---- stage chunk 0 -----------------------------------------------------
  StageRegs st;
  stage_issue(st, h0p, h1p, x, 0, sx, tid);
  stage_commit(st, lds + BUF0, tid);
  __syncthreads();

  float acc[16];
  #pragma unroll
  for (int i = 0; i < 16; ++i) acc[i] = 0.f;

  // ---- main chunk loop (double-buffered, write-late) ---------------------
  for (int c = 0; c < NCH; ++c) {
    if (c < NCH - 1) stage_issue(st, h0p, h1p, x, c + 1, sx, tid);

    const float* buf = lds + ((c & 1) ? BUF1 : BUF0);
    if (L == 0) {
      if (l0h_act) dot6<8, 768>(acc, buf,        kq * 8, lds + WL0_OFF,
                                c * CHK + kq * 8, lane2, false);
      if (l0_act)  dot6<4, 768>(acc, buf + 8192, kq * 4, lds + WL0_OFF,
                                512 + c * XCH + kq * 4, lane2, true);
    } else {
      if (l1h_act) dot6<8, 1024>(acc, buf + 4096, kq * 8, lds + WL1_OFF,
                                 c * CHK + kq * 8, lane2, false);
      if (l1_act)  dot6<8, 1024>(acc, buf,        kq * 8, lds + WL1_OFF,
                                 512 + c * CHK + kq * 8, lane2, true);
    }

    if (c < NCH - 1) stage_commit(st, lds + (((c + 1) & 1) ? BUF1 : BUF0), tid);
    __syncthreads();
  }

  // ---- k-quarter reduction ----------------------------------------------
  if (kq != 0) {
    float* rb = lds + RB_OFF + (L * 3 + (kq - 1)) * 1024;
    #pragma unroll
    for (int i = 0; i < 16; ++i) rb[i * 64 + lane] = acc[i];
  }
  __syncthreads();

  if (kq == 0) {
    const float* rb = lds + RB_OFF + L * 3 * 1024;
    #pragma unroll
    for (int sl = 0; sl < 3; ++sl) {
      #pragma unroll
      for (int i = 0; i < 16; ++i) acc[i] += rb[sl * 1024 + i * 64 + lane];
    }

    const bool act = L ? l1_act : l0_act;
    if (act) {
      const float* bi  = L ? bih1 : bih0;
      const float* bh  = L ? bhh1 : bhh0;
      const float* hp  = L ? h1p : h0p;
      float*       hw  = L ? h1w : h0w;
      const bool hv_ok = L ? l1h_act : l0h_act;
      #pragma unroll
      for (int jj = 0; jj < 2; ++jj) {
        const int j = j0 + jj;
        float2 hpre = make_float2(0.f, 0.f);
        if (hv_ok) hpre = *(const float2*)(hp + j * B_SZ + lane2);
        float2 ho;
        #pragma unroll
        for (int bb = 0; bb < 2; ++bb) {
          const float ar  = acc[((0 * 2 + jj) << 1) + bb];
          const float az  = acc[((1 * 2 + jj) << 1) + bb];
          const float anh = acc[((2 * 2 + jj) << 1) + bb];
          const float anx = acc[((3 * 2 + jj) << 1) + bb];
          const float r = sigm(ar + bi[j] + bh[j]);
          const float z = sigm(az + bi[H_SZ + j] + bh[H_SZ + j]);
          const float n = tanhf(anx + bi[2 * H_SZ + j] + r * (anh + bh[2 * H_SZ + j]));
          const float hq = bb ? hpre.y : hpre.x;
          const float hn = (1.f - z) * n + z * hq;
          if (bb) ho.y = hn; else ho.x = hn;
        }
        *(float2*)(hw + j * B_SZ + lane2) = ho;
      }
    }
  }
}

// out[b] = sum_j h1f[j][b] * wlin[j] + blin[0]
__global__ void __launch_bounds__(512)
final_linear(const float* __restrict__ h1f, const float* __restrict__ wlin,
             const float* __restrict__ blin, float* __restrict__ out)
{
  __shared__ float red[4][B_SZ];
  const int b  = threadIdx.x & 127;
  const int jq = threadIdx.x >> 7;
  float acc = 0.f;
  #pragma unroll 8
  for (int j = jq * 128; j < jq * 128 + 128; ++j)
    acc = fmaf(h1f[j * B_SZ + b], wlin[j], acc);
  red[jq][b] = acc;
  __syncthreads();
  if (jq == 0)
    out[b] = red[0][b] + red[1][b] + red[2][b] + red[3][b] + blin[0];
}

extern "C" void kernel_launch(void* const* d_in, const int* in_sizes, int n_in,
                              void* d_out, int out_size, void* d_ws, size_t ws_size,
                              hipStream_t stream) {
  const float* x    = (const float*)d_in[0];
  const float* Wih0 = (const float*)d_in[1];
  const float* Whh0 = (const float*)d_in[2];
  const float* bih0 = (const float*)d_in[3];
  const float* bhh0 = (const float*)d_in[4];
  const float* Wih1 = (const float*)d_in[5];
  const float* Whh1 = (const float*)d_in[6];
  const float* bih1 = (const float*)d_in[7];
  const float* bhh1 = (const float*)d_in[8];
  const float* Wlin = (const float*)d_in[9];
  const float* blin = (const float*)d_in[10];

  // ws: 4 h buffers [512 j][128 b] fp32, 1 MB total.
  float* ws = (float*)d_ws;
  float* h0b[2] = { ws,             ws + 1 * HBUF };
  float* h1b[2] = { ws + 2 * HBUF, ws + 3 * HBUF };

  static int attr_done = 0;   // idempotent, capture-safe (not a stream op)
  if (!attr_done) {
    hipFuncSetAttribute((const void*)gru_step,
                        hipFuncAttributeMaxDynamicSharedMemorySize, LDS_BYTES);
    attr_done = 1;
  }

  for (int s = 0; s <= T_LEN; ++s) {
    const int rp = s & 1, wp = rp ^ 1;
    gru_step<<<dim3(256), dim3(512), LDS_BYTES, stream>>>(
        s, x, Wih0, Whh0, bih0, bhh0, Wih1, Whh1, bih1, bhh1,
        h0b[rp], h0b[wp], h1b[rp], h1b[wp]);
  }
  // L1 @ t=1023 computed at s=1024, written to parity (1024&1)^1 = 1.
  final_linear<<<dim3(1), dim3(512), 0, stream>>>(h1b[1], Wlin, blin, (float*)d_out);
}